// Round 1
// baseline (445.127 us; speedup 1.0000x reference)
//
#include <hip/hip_runtime.h>
#include <hip/hip_bf16.h>

#define B_ 4
#define N_ 16384
#define K_ 16
#define NEG 0.2f
#define EPSBN 1e-5f
#define INV_SIG2 2500.0f

typedef unsigned short u16;
typedef unsigned int   u32;

__device__ __forceinline__ float bf2f(u16 h){
  return __uint_as_float(((u32)h) << 16);
}
__device__ __forceinline__ u16 f2bf(float f){
  u32 x = __float_as_uint(f);
  x += 0x7fffu + ((x >> 16) & 1u);
  return (u16)(x >> 16);
}

// ---------------- K1: u = (W1-W2)^T x, v = W2^T x, stored [B][N][64] bf16 --------
// grid (N/128, B), block 256. Register-tiled 128x128 GEMM, K=64.
__global__ __launch_bounds__(256) void k1_uv(const float* __restrict__ x,
                                             const float* __restrict__ we,
                                             u16* __restrict__ uo,
                                             u16* __restrict__ vo){
  const int n0 = blockIdx.x * 128;
  const int b  = blockIdx.y;
  __shared__ u16   Wl[64*128];   // [c'][r] bf16, r<64 -> WA=W1-W2, r>=64 -> WB=W2
  __shared__ float Xl[64*128];   // [c'][n]
  const int tid = threadIdx.x;
  for (int idx = tid; idx < 64*128; idx += 256){
    const int cp = idx >> 7, r = idx & 127;
    float w;
    if (r < 64) w = we[r*128 + cp] - we[r*128 + 64 + cp];
    else        w = we[(r-64)*128 + 64 + cp];
    Wl[cp*128 + r] = f2bf(w);
  }
  for (int idx = tid; idx < 64*128; idx += 256){
    const int cp = idx >> 7, nl = idx & 127;
    Xl[cp*128 + nl] = x[(b*64 + cp)*N_ + n0 + nl];
  }
  __syncthreads();
  const int tr = tid & 15, tc = tid >> 4;   // r-base = tr*8, n-base = tc*8
  float acc[8][8];
  #pragma unroll
  for (int i=0;i<8;++i)
    #pragma unroll
    for (int j=0;j<8;++j) acc[i][j] = 0.f;
  for (int cp=0; cp<64; ++cp){
    const uint4 wv = *(const uint4*)&Wl[cp*128 + tr*8];
    float wr[8];
    wr[0]=__uint_as_float(wv.x<<16); wr[1]=__uint_as_float(wv.x & 0xffff0000u);
    wr[2]=__uint_as_float(wv.y<<16); wr[3]=__uint_as_float(wv.y & 0xffff0000u);
    wr[4]=__uint_as_float(wv.z<<16); wr[5]=__uint_as_float(wv.z & 0xffff0000u);
    wr[6]=__uint_as_float(wv.w<<16); wr[7]=__uint_as_float(wv.w & 0xffff0000u);
    const float4 x0 = *(const float4*)&Xl[cp*128 + tc*8];
    const float4 x1 = *(const float4*)&Xl[cp*128 + tc*8 + 4];
    const float xr[8] = {x0.x,x0.y,x0.z,x0.w,x1.x,x1.y,x1.z,x1.w};
    #pragma unroll
    for (int i=0;i<8;++i)
      #pragma unroll
      for (int j=0;j<8;++j)
        acc[i][j] = fmaf(wr[i], xr[j], acc[i][j]);
  }
  u16* dst = (tr < 8) ? uo : vo;
  const int cb = (tr & 7) * 8;
  #pragma unroll
  for (int ni=0; ni<8; ++ni){
    const int n = n0 + tc*8 + ni;
    u32 p0 = (u32)f2bf(acc[0][ni]) | ((u32)f2bf(acc[1][ni]) << 16);
    u32 p1 = (u32)f2bf(acc[2][ni]) | ((u32)f2bf(acc[3][ni]) << 16);
    u32 p2 = (u32)f2bf(acc[4][ni]) | ((u32)f2bf(acc[5][ni]) << 16);
    u32 p3 = (u32)f2bf(acc[6][ni]) | ((u32)f2bf(acc[7][ni]) << 16);
    *(uint4*)&dst[(b*N_ + n)*64 + cb] = make_uint4(p0,p1,p2,p3);
  }
}

// ---------------- K2: gather h = u[i]+v[j]; per-(b,n) max/min over k; global sum/sumsq
// grid (N/64, B), block 256 (4 waves, one n per wave-iteration, lane = channel)
__global__ __launch_bounds__(256) void k2_gather(const u16* __restrict__ uo,
                                                 const u16* __restrict__ vo,
                                                 const int* __restrict__ eidx,
                                                 u16* __restrict__ wmaxo,
                                                 u16* __restrict__ wmino,
                                                 float* __restrict__ stats){
  const int n0 = blockIdx.x * 64;
  const int b  = blockIdx.y;
  const int tid = threadIdx.x;
  const int wid = tid >> 6, lane = tid & 63;
  const u16* ub = uo + b*N_*64;
  const u16* vb = vo + b*N_*64;
  float ssum = 0.f, ssq = 0.f;
  __shared__ float red[2][4][64];
  for (int i=0; i<16; ++i){
    const int n = n0 + wid*16 + i;
    int raw = 0;
    if (lane < 32)
      raw = eidx[(lane >> 4)*(B_*N_*K_) + (b*N_ + n)*K_ + (lane & 15)];
    // lanes 0..15 hold edge_index[0] (j / neighbor), lanes 16..31 hold edge_index[1] (i / center)
    float hmax = -1e30f, hmin = 1e30f;
    #pragma unroll
    for (int k=0;k<16;++k){
      const int jj = __shfl(raw, k);
      const int ii = __shfl(raw, 16+k);
      const float h = bf2f(ub[ii*64 + lane]) + bf2f(vb[jj*64 + lane]);
      hmax = fmaxf(hmax, h);
      hmin = fminf(hmin, h);
      ssum += h;
      ssq = fmaf(h, h, ssq);
    }
    wmaxo[(b*N_ + n)*64 + lane] = f2bf(hmax);
    wmino[(b*N_ + n)*64 + lane] = f2bf(hmin);
  }
  red[0][wid][lane] = ssum;
  red[1][wid][lane] = ssq;
  __syncthreads();
  if (wid == 0){
    atomicAdd(&stats[lane],
      red[0][0][lane]+red[0][1][lane]+red[0][2][lane]+red[0][3][lane]);
  } else if (wid == 1){
    atomicAdd(&stats[64+lane],
      red[1][0][lane]+red[1][1][lane]+red[1][2][lane]+red[1][3][lane]);
  }
}

// ---------------- K3: finalize BN affine: sct[c]=scale, sct[64+c]=shift ----------
__global__ void k3_finalize(const float* __restrict__ stats,
                            const float* __restrict__ gamma,
                            const float* __restrict__ beta,
                            float* __restrict__ sct){
  const int c = threadIdx.x;
  const float inv = 1.0f / (float)(B_*N_*K_);
  const float mean = stats[c] * inv;
  const float var  = stats[64+c] * inv - mean*mean;
  const float s = gamma[c] * rsqrtf(var + EPSBN);
  sct[c] = s;
  sct[64+c] = beta[c] - mean*s;
}

// ---------------- K4: weighted conv. grid (N/128, 4, B), block 128 ----------------
// o-tile 32, n-tile 128; per-thread 4o x 8n; wc bf16 in LDS; h tile bf16 in LDS.
__global__ __launch_bounds__(128) void k4_conv(const u16* __restrict__ wmaxo,
                                               const u16* __restrict__ wmino,
                                               const float* __restrict__ sct,
                                               const float* __restrict__ coords,
                                               const float* __restrict__ wconv,
                                               const float* __restrict__ bconv,
                                               float* __restrict__ out){
  const int n0 = blockIdx.x * 128;
  const int ob = blockIdx.y * 32;
  const int b  = blockIdx.z;
  __shared__ u16 wcl[576*32];   // [(c*9+j)][olocal] bf16  36.9KB
  __shared__ u16 hl[64*144];    // [c][ml 0..135] bf16 (pad 144) 18.4KB
  const int tid = threadIdx.x;
  for (int idx = tid; idx < 576*32; idx += 128){
    const int cj = idx >> 5, ol = idx & 31;
    wcl[idx] = f2bf(wconv[(ob + ol)*576 + cj]);
  }
  // h tile: apply BN affine + leaky to max (or min if scale<0); zero-pad outside
  for (int idx = tid; idx < 136*64; idx += 128){
    const int ml = idx >> 6, c = idx & 63;
    const int m = n0 - 4 + ml;
    float hv = 0.f;
    if (m >= 0 && m < N_){
      const float s = sct[c];
      const float t = sct[64+c];
      const u16 mv = (s >= 0.f) ? wmaxo[(b*N_+m)*64+c] : wmino[(b*N_+m)*64+c];
      hv = fmaf(s, bf2f(mv), t);
      hv = (hv >= 0.f) ? hv : NEG*hv;
    }
    hl[c*144 + ml] = f2bf(hv);
  }
  __syncthreads();
  const int ns = tid & 15, os = tid >> 4;   // n-base = ns*8, o-local base = os*4
  // coordinate window (16 positions covering all 8 n x 9 j offsets)
  float cw[3][16];
  #pragma unroll
  for (int d=0; d<3; ++d){
    #pragma unroll
    for (int q=0; q<16; ++q){
      int m = n0 + ns*8 - 4 + q;
      m = m < 0 ? 0 : (m >= N_ ? N_-1 : m);
      cw[d][q] = coords[(b*3 + d)*N_ + m];
    }
  }
  float wgt[72];
  #pragma unroll
  for (int j=0;j<9;++j){
    #pragma unroll
    for (int nn=0;nn<8;++nn){
      const int m = n0 + ns*8 + nn - 4 + j;
      const float dx = cw[0][nn+j] - cw[0][nn+4];
      const float dy = cw[1][nn+j] - cw[1][nn+4];
      const float dz = cw[2][nn+j] - cw[2][nn+4];
      const float d2 = fmaf(dx,dx, fmaf(dy,dy, dz*dz));
      wgt[j*8+nn] = (m >= 0 && m < N_) ? __expf(-INV_SIG2 * d2) : 0.f;
    }
  }
  float acc[4][8];
  #pragma unroll
  for (int i=0;i<4;++i)
    #pragma unroll
    for (int j=0;j<8;++j) acc[i][j] = 0.f;

  for (int c=0; c<64; ++c){
    const uint4 ha = *(const uint4*)&hl[c*144 + ns*8];
    const uint4 hb = *(const uint4*)&hl[c*144 + ns*8 + 8];
    float hr[16];
    hr[0] =__uint_as_float(ha.x<<16); hr[1] =__uint_as_float(ha.x & 0xffff0000u);
    hr[2] =__uint_as_float(ha.y<<16); hr[3] =__uint_as_float(ha.y & 0xffff0000u);
    hr[4] =__uint_as_float(ha.z<<16); hr[5] =__uint_as_float(ha.z & 0xffff0000u);
    hr[6] =__uint_as_float(ha.w<<16); hr[7] =__uint_as_float(ha.w & 0xffff0000u);
    hr[8] =__uint_as_float(hb.x<<16); hr[9] =__uint_as_float(hb.x & 0xffff0000u);
    hr[10]=__uint_as_float(hb.y<<16); hr[11]=__uint_as_float(hb.y & 0xffff0000u);
    hr[12]=__uint_as_float(hb.z<<16); hr[13]=__uint_as_float(hb.z & 0xffff0000u);
    hr[14]=__uint_as_float(hb.w<<16); hr[15]=__uint_as_float(hb.w & 0xffff0000u);
    #pragma unroll
    for (int j=0;j<9;++j){
      const ushort4 wc4 = *(const ushort4*)&wcl[(c*9+j)*32 + os*4];
      const float w0 = bf2f(wc4.x), w1 = bf2f(wc4.y);
      const float w2 = bf2f(wc4.z), w3 = bf2f(wc4.w);
      #pragma unroll
      for (int nn=0;nn<8;++nn){
        const float th = wgt[j*8+nn] * hr[nn+j];
        acc[0][nn] = fmaf(w0, th, acc[0][nn]);
        acc[1][nn] = fmaf(w1, th, acc[1][nn]);
        acc[2][nn] = fmaf(w2, th, acc[2][nn]);
        acc[3][nn] = fmaf(w3, th, acc[3][nn]);
      }
    }
  }
  #pragma unroll
  for (int oi=0; oi<4; ++oi){
    const int o = ob + os*4 + oi;
    const float bs = bconv[o];
    float* dst = &out[(b*128 + o)*N_ + n0 + ns*8];
    float4 r0 = make_float4(acc[oi][0]+bs, acc[oi][1]+bs, acc[oi][2]+bs, acc[oi][3]+bs);
    float4 r1 = make_float4(acc[oi][4]+bs, acc[oi][5]+bs, acc[oi][6]+bs, acc[oi][7]+bs);
    *(float4*)dst = r0;
    *((float4*)dst + 1) = r1;
  }
}

extern "C" void kernel_launch(void* const* d_in, const int* in_sizes, int n_in,
                              void* d_out, int out_size, void* d_ws, size_t ws_size,
                              hipStream_t stream){
  const float* x      = (const float*)d_in[0];
  const float* coords = (const float*)d_in[1];
  const int*   eidx   = (const int*)  d_in[2];
  const float* we     = (const float*)d_in[3];
  const float* gamma  = (const float*)d_in[4];
  const float* beta   = (const float*)d_in[5];
  const float* wconv  = (const float*)d_in[6];
  const float* bconv  = (const float*)d_in[7];
  float* out = (float*)d_out;
  char* ws = (char*)d_ws;
  // ws layout (bytes): u[8.39MB] v[8.39MB] wmax[8.39MB] wmin[8.39MB] stats[512] sct[512]
  u16* u     = (u16*)(ws);
  u16* v     = (u16*)(ws + 8388608);
  u16* wmax_ = (u16*)(ws + 16777216);
  u16* wmin_ = (u16*)(ws + 25165824);
  float* stats = (float*)(ws + 33554432);
  float* sct   = (float*)(ws + 33554432 + 512);

  hipMemsetAsync(stats, 0, 512, stream);
  k1_uv<<<dim3(N_/128, B_), 256, 0, stream>>>(x, we, u, v);
  k2_gather<<<dim3(N_/64, B_), 256, 0, stream>>>(u, v, eidx, wmax_, wmin_, stats);
  k3_finalize<<<1, 64, 0, stream>>>(stats, gamma, beta, sct);
  k4_conv<<<dim3(N_/128, 4, B_), 128, 0, stream>>>(wmax_, wmin_, sct, coords, wconv, bconv, out);
}

// Round 2
// 141.015 us; speedup vs baseline: 3.1566x; 3.1566x over previous
//
#include <hip/hip_runtime.h>
#include <hip/hip_bf16.h>

#define B_ 4
#define N_ 16384
#define K_ 16
#define NEG 0.2f
#define EPSBN 1e-5f
#define INV_SIG2 2500.0f

typedef unsigned short u16;
typedef unsigned int   u32;
typedef __attribute__((ext_vector_type(8))) short short8;
typedef __attribute__((ext_vector_type(4))) float f32x4;

__device__ __forceinline__ float bf2f(u16 h){
  return __uint_as_float(((u32)h) << 16);
}
__device__ __forceinline__ u16 f2bf(float f){
  u32 x = __float_as_uint(f);
  x += 0x7fffu + ((x >> 16) & 1u);
  return (u16)(x >> 16);
}

// ---------------- K0: wconv [o][c][j] fp32 -> wbf [j][o][c] bf16 ----------------
__global__ void k0_wprep(const float* __restrict__ wconv, u16* __restrict__ wbf){
  const int idx = blockIdx.x * 256 + threadIdx.x;
  if (idx < 9*128*64){
    const int j = idx >> 13;
    const int rem = idx & 8191;
    const int o = rem >> 6, c = rem & 63;
    wbf[idx] = f2bf(wconv[(o*64 + c)*9 + j]);
  }
}

// ---------------- K1: u = (W1-W2)^T x, v = W2^T x, stored [B][N][64] bf16 --------
__global__ __launch_bounds__(256) void k1_uv(const float* __restrict__ x,
                                             const float* __restrict__ we,
                                             u16* __restrict__ uo,
                                             u16* __restrict__ vo){
  const int n0 = blockIdx.x * 128;
  const int b  = blockIdx.y;
  __shared__ u16   Wl[64*128];   // [c'][r] bf16, r<64 -> WA=W1-W2, r>=64 -> WB=W2
  __shared__ float Xl[64*128];   // [c'][n]
  const int tid = threadIdx.x;
  for (int idx = tid; idx < 64*128; idx += 256){
    const int cp = idx >> 7, r = idx & 127;
    float w;
    if (r < 64) w = we[r*128 + cp] - we[r*128 + 64 + cp];
    else        w = we[(r-64)*128 + 64 + cp];
    Wl[cp*128 + r] = f2bf(w);
  }
  for (int idx = tid; idx < 64*128; idx += 256){
    const int cp = idx >> 7, nl = idx & 127;
    Xl[cp*128 + nl] = x[(b*64 + cp)*N_ + n0 + nl];
  }
  __syncthreads();
  const int tr = tid & 15, tc = tid >> 4;
  float acc[8][8];
  #pragma unroll
  for (int i=0;i<8;++i)
    #pragma unroll
    for (int j=0;j<8;++j) acc[i][j] = 0.f;
  for (int cp=0; cp<64; ++cp){
    const uint4 wv = *(const uint4*)&Wl[cp*128 + tr*8];
    float wr[8];
    wr[0]=__uint_as_float(wv.x<<16); wr[1]=__uint_as_float(wv.x & 0xffff0000u);
    wr[2]=__uint_as_float(wv.y<<16); wr[3]=__uint_as_float(wv.y & 0xffff0000u);
    wr[4]=__uint_as_float(wv.z<<16); wr[5]=__uint_as_float(wv.z & 0xffff0000u);
    wr[6]=__uint_as_float(wv.w<<16); wr[7]=__uint_as_float(wv.w & 0xffff0000u);
    const float4 x0 = *(const float4*)&Xl[cp*128 + tc*8];
    const float4 x1 = *(const float4*)&Xl[cp*128 + tc*8 + 4];
    const float xr[8] = {x0.x,x0.y,x0.z,x0.w,x1.x,x1.y,x1.z,x1.w};
    #pragma unroll
    for (int i=0;i<8;++i)
      #pragma unroll
      for (int j=0;j<8;++j)
        acc[i][j] = fmaf(wr[i], xr[j], acc[i][j]);
  }
  u16* dst = (tr < 8) ? uo : vo;
  const int cb = (tr & 7) * 8;
  #pragma unroll
  for (int ni=0; ni<8; ++ni){
    const int n = n0 + tc*8 + ni;
    u32 p0 = (u32)f2bf(acc[0][ni]) | ((u32)f2bf(acc[1][ni]) << 16);
    u32 p1 = (u32)f2bf(acc[2][ni]) | ((u32)f2bf(acc[3][ni]) << 16);
    u32 p2 = (u32)f2bf(acc[4][ni]) | ((u32)f2bf(acc[5][ni]) << 16);
    u32 p3 = (u32)f2bf(acc[6][ni]) | ((u32)f2bf(acc[7][ni]) << 16);
    *(uint4*)&dst[(b*N_ + n)*64 + cb] = make_uint4(p0,p1,p2,p3);
  }
}

// ---------------- K2: gather h = u[i]+v[j]; per-(b,n) max/min over k; global sum/sumsq
__global__ __launch_bounds__(256) void k2_gather(const u16* __restrict__ uo,
                                                 const u16* __restrict__ vo,
                                                 const int* __restrict__ eidx,
                                                 u16* __restrict__ wmaxo,
                                                 u16* __restrict__ wmino,
                                                 float* __restrict__ stats){
  const int n0 = blockIdx.x * 64;
  const int b  = blockIdx.y;
  const int tid = threadIdx.x;
  const int wid = tid >> 6, lane = tid & 63;
  const u16* ub = uo + b*N_*64;
  const u16* vb = vo + b*N_*64;
  float ssum = 0.f, ssq = 0.f;
  __shared__ float red[2][4][64];
  for (int i=0; i<16; ++i){
    const int n = n0 + wid*16 + i;
    int raw = 0;
    if (lane < 32)
      raw = eidx[(lane >> 4)*(B_*N_*K_) + (b*N_ + n)*K_ + (lane & 15)];
    float hmax = -1e30f, hmin = 1e30f;
    #pragma unroll
    for (int k=0;k<16;++k){
      const int jj = __shfl(raw, k);
      const int ii = __shfl(raw, 16+k);
      const float h = bf2f(ub[ii*64 + lane]) + bf2f(vb[jj*64 + lane]);
      hmax = fmaxf(hmax, h);
      hmin = fminf(hmin, h);
      ssum += h;
      ssq = fmaf(h, h, ssq);
    }
    wmaxo[(b*N_ + n)*64 + lane] = f2bf(hmax);
    wmino[(b*N_ + n)*64 + lane] = f2bf(hmin);
  }
  red[0][wid][lane] = ssum;
  red[1][wid][lane] = ssq;
  __syncthreads();
  if (wid == 0){
    atomicAdd(&stats[lane],
      red[0][0][lane]+red[0][1][lane]+red[0][2][lane]+red[0][3][lane]);
  } else if (wid == 1){
    atomicAdd(&stats[64+lane],
      red[1][0][lane]+red[1][1][lane]+red[1][2][lane]+red[1][3][lane]);
  }
}

// ---------------- K3: finalize BN affine: sct[c]=scale, sct[64+c]=shift ----------
__global__ void k3_finalize(const float* __restrict__ stats,
                            const float* __restrict__ gamma,
                            const float* __restrict__ beta,
                            float* __restrict__ sct){
  const int c = threadIdx.x;
  const float inv = 1.0f / (float)(B_*N_*K_);
  const float mean = stats[c] * inv;
  const float var  = stats[64+c] * inv - mean*mean;
  const float s = gamma[c] * rsqrtf(var + EPSBN);
  sct[c] = s;
  sct[64+c] = beta[c] - mean*s;
}

// ---------------- K4: MFMA weighted conv ------------------------------------------
// grid (N/64, B), block 256 (4 waves). Wave w: o in [w*32, w*32+32), n-tile 64.
// out[o][n] = sum_j wgt[j][n] * (Wj x hbn_shift_j)[o][n] + bias
__global__ __launch_bounds__(256) void k4_mfma(const u16* __restrict__ wmaxo,
                                               const u16* __restrict__ wmino,
                                               const float* __restrict__ sct,
                                               const float* __restrict__ coords,
                                               const u16* __restrict__ wbf,
                                               const float* __restrict__ bconv,
                                               float* __restrict__ out){
  const int n0 = blockIdx.x * 64;
  const int b  = blockIdx.y;
  const int tid = threadIdx.x;
  const int w = tid >> 6, lane = tid & 63;
  const int r15 = lane & 15, kg = lane >> 4;

  __shared__ u16 hl[72*72];     // [m_local][c], row stride 72 (pad) -> 10.4 KB
  __shared__ float wgt[9*64];   // [j][n] Gaussian weights

  // --- build hbn tile: h = leaky(s*max_or_min + t), rows m = n0-4 .. n0+67
  {
    const int c = tid & 63;
    const float s = sct[c], t = sct[64+c];
    const u16* src = ((s >= 0.f) ? wmaxo : wmino) + (size_t)b*N_*64 + c;
    #pragma unroll
    for (int it = 0; it < 18; ++it){
      const int ml = (tid >> 6) + it*4;
      const int m = n0 - 4 + ml;
      float hv = 0.f;
      if (m >= 0 && m < N_){
        hv = fmaf(s, bf2f(src[(size_t)m*64]), t);
        hv = (hv >= 0.f) ? hv : NEG*hv;
      }
      hl[ml*72 + c] = f2bf(hv);
    }
  }
  // --- build Gaussian weights wgt[j][n]
  for (int idx = tid; idx < 576; idx += 256){
    const int j = idx >> 6, n = idx & 63;
    const int mc = n0 + n, mt = mc + j - 4;
    float wv = 0.f;
    if (mt >= 0 && mt < N_){
      float d2 = 0.f;
      #pragma unroll
      for (int d = 0; d < 3; ++d){
        const float dd = coords[(b*3+d)*N_ + mt] - coords[(b*3+d)*N_ + mc];
        d2 = fmaf(dd, dd, d2);
      }
      wv = __expf(-INV_SIG2 * d2);
    }
    wgt[idx] = wv;
  }
  __syncthreads();

  // --- MFMA main loop over taps j
  const u16* abase = wbf + ((w*32 + r15)*64 + kg*8);   // + j*8192 + of*1024 + cc
  const u16* hbase = &hl[r15*72 + kg*8];               // + (nf*16 + j)*72 + cc
  f32x4 acc[2][4] = {};
  const f32x4 zero = {0.f, 0.f, 0.f, 0.f};

  for (int j = 0; j < 9; ++j){
    float wj[4];
    #pragma unroll
    for (int nf = 0; nf < 4; ++nf) wj[nf] = wgt[j*64 + nf*16 + r15];
    short8 bfr[4][2];
    #pragma unroll
    for (int nf = 0; nf < 4; ++nf){
      bfr[nf][0] = *(const short8*)&hbase[(nf*16 + j)*72];
      bfr[nf][1] = *(const short8*)&hbase[(nf*16 + j)*72 + 32];
    }
    #pragma unroll
    for (int of = 0; of < 2; ++of){
      const short8 a0 = *(const short8*)&abase[j*8192 + of*1024];
      const short8 a1 = *(const short8*)&abase[j*8192 + of*1024 + 32];
      #pragma unroll
      for (int nf = 0; nf < 4; ++nf){
        f32x4 p = __builtin_amdgcn_mfma_f32_16x16x32_bf16(a0, bfr[nf][0], zero, 0, 0, 0);
        p = __builtin_amdgcn_mfma_f32_16x16x32_bf16(a1, bfr[nf][1], p, 0, 0, 0);
        #pragma unroll
        for (int r = 0; r < 4; ++r)
          acc[of][nf][r] = fmaf(wj[nf], p[r], acc[of][nf][r]);
      }
    }
  }

  // --- epilogue: D layout col = lane&15, row = (lane>>4)*4 + reg
  #pragma unroll
  for (int of = 0; of < 2; ++of){
    #pragma unroll
    for (int r = 0; r < 4; ++r){
      const int o = w*32 + of*16 + kg*4 + r;
      const float bs = bconv[o];
      float* dst = &out[(size_t)(b*128 + o)*N_ + n0 + r15];
      #pragma unroll
      for (int nf = 0; nf < 4; ++nf)
        dst[nf*16] = acc[of][nf][r] + bs;
    }
  }
}

extern "C" void kernel_launch(void* const* d_in, const int* in_sizes, int n_in,
                              void* d_out, int out_size, void* d_ws, size_t ws_size,
                              hipStream_t stream){
  const float* x      = (const float*)d_in[0];
  const float* coords = (const float*)d_in[1];
  const int*   eidx   = (const int*)  d_in[2];
  const float* we     = (const float*)d_in[3];
  const float* gamma  = (const float*)d_in[4];
  const float* beta   = (const float*)d_in[5];
  const float* wconv  = (const float*)d_in[6];
  const float* bconv  = (const float*)d_in[7];
  float* out = (float*)d_out;
  char* ws = (char*)d_ws;
  // ws layout (bytes): u[8.39MB] v[8.39MB] wmax[8.39MB] wmin[8.39MB] stats[512] sct[512] wbf[147KB]
  u16* u     = (u16*)(ws);
  u16* v     = (u16*)(ws + 8388608);
  u16* wmax_ = (u16*)(ws + 16777216);
  u16* wmin_ = (u16*)(ws + 25165824);
  float* stats = (float*)(ws + 33554432);
  float* sct   = (float*)(ws + 33554944);
  u16* wbf     = (u16*)(ws + 33555456);

  hipMemsetAsync(stats, 0, 512, stream);
  k0_wprep<<<288, 256, 0, stream>>>(wconv, wbf);
  k1_uv<<<dim3(N_/128, B_), 256, 0, stream>>>(x, we, u, v);
  k2_gather<<<dim3(N_/64, B_), 256, 0, stream>>>(u, v, eidx, wmax_, wmin_, stats);
  k3_finalize<<<1, 64, 0, stream>>>(stats, gamma, beta, sct);
  k4_mfma<<<dim3(N_/64, B_), 256, 0, stream>>>(wmax_, wmin_, sct, coords, wbf, bconv, out);
}